// Round 3
// baseline (347.060 us; speedup 1.0000x reference)
//
#include <hip/hip_runtime.h>
#include <stdint.h>

typedef uint16_t u16;
typedef __attribute__((ext_vector_type(8))) short bf16x8;    // 8 bf16 (4 VGPRs)
typedef __attribute__((ext_vector_type(8))) uint16_t u16x8;
typedef __attribute__((ext_vector_type(4))) uint16_t u16x4;
typedef __attribute__((ext_vector_type(4))) float f32x4;     // MFMA C/D

#define EMB 768
#define NH 12
#define DK 64
#define BB 2
#define SS 2048
#define LOG2E 1.4426950408889634f

// round-to-nearest-even f32 -> bf16
__device__ __forceinline__ u16 f2bf(float x) {
  union { float f; uint32_t u; } v; v.f = x;
  uint32_t r = v.u + 0x7fffu + ((v.u >> 16) & 1u);
  return (u16)(r >> 16);
}

__device__ __forceinline__ void gld16(const u16* g, u16* l) {
  __builtin_amdgcn_global_load_lds((const __attribute__((address_space(1))) void*)g,
                                   (__attribute__((address_space(3))) void*)l, 16, 0, 0);
}

// ---------------- pack kernels (f32 weights -> bf16, B^T layouts) ----------------
// WqkvT[p][n][e] = Wp[h][e][d], n = h*64+d
__global__ void pack_wqkv(const float* __restrict__ wq, const float* __restrict__ wk,
                          const float* __restrict__ wv, u16* __restrict__ out) {
  const float* w = blockIdx.y == 0 ? wq : (blockIdx.y == 1 ? wk : wv);
  u16* o = out + (size_t)blockIdx.y * EMB * EMB;
  int t = blockIdx.x * 256 + threadIdx.x;       // over 768*768
  int n = t / EMB, e = t - n * EMB;
  int h = n >> 6, d = n & 63;
  o[t] = f2bf(w[(h * EMB + e) * DK + d]);
}

// WT[n][e] = W[e][n]
__global__ void pack_wt(const float* __restrict__ w, u16* __restrict__ o) {
  int t = blockIdx.x * 256 + threadIdx.x;
  int n = t / EMB, e = t - n * EMB;
  o[t] = f2bf(w[e * EMB + n]);
}

// bit-pack mask: bit t%32 of word [(b*S+s)*64 + t/32]
__global__ void pack_mask(const int* __restrict__ mask, uint32_t* __restrict__ bits) {
  size_t t = (size_t)blockIdx.x * 256 + threadIdx.x;
  int m = mask[t];
  unsigned long long ball = __ballot(m != 0);
  if ((threadIdx.x & 31) == 0)
    bits[t >> 5] = (uint32_t)((threadIdx.x & 32) ? (ball >> 32) : ball);
}

// ---------------- GEMM cores (C = A[M,K] * Bt[N,K]^T), 128x128 tile ----------------
// MFMA fragment part shared by both variants
#define GEMM_MFMA_BODY                                                          \
    bf16x8 af[4], bfr[4];                                                       \
    _Pragma("unroll")                                                           \
    for (int i = 0; i < 4; ++i)                                                 \
      af[i] = *(const bf16x8*)(As + (wr * 64 + i * 16 + c) * 32 + quad * 8);    \
    _Pragma("unroll")                                                           \
    for (int j = 0; j < 4; ++j)                                                 \
      bfr[j] = *(const bf16x8*)(Bs + (wc * 64 + j * 16 + c) * 32 + quad * 8);   \
    _Pragma("unroll")                                                           \
    for (int i = 0; i < 4; ++i)                                                 \
      _Pragma("unroll")                                                         \
      for (int j = 0; j < 4; ++j)                                               \
        acc[i][j] = __builtin_amdgcn_mfma_f32_16x16x32_bf16(af[i], bfr[j], acc[i][j], 0, 0, 0);

// A is float32 in global (converted to bf16 while staging); Bt is packed bf16.
__device__ __forceinline__ void gemm_tile_f32A(const float* __restrict__ A,
                                               const u16* __restrict__ Bt, int Kdim,
                                               int m0, int n0, u16* As, u16* Bs,
                                               f32x4 (&acc)[4][4]) {
  const int tid = threadIdx.x;
  const int lane = tid & 63, quad = lane >> 4, c = lane & 15;
  const int wr = (tid >> 6) >> 1, wc = (tid >> 6) & 1;
  for (int kk = 0; kk < Kdim; kk += 32) {
    __syncthreads();
#pragma unroll
    for (int r = 0; r < 2; ++r) {                 // Bs: 128x32 bf16 via direct-to-LDS
      int bo = r * 4096 + tid * 16;
      int row = bo >> 6, colb = bo & 63;
      gld16(Bt + (size_t)(n0 + row) * Kdim + kk + (colb >> 1), (u16*)((char*)Bs + bo));
    }
#pragma unroll
    for (int p = 0; p < 2; ++p) {                 // As: 128x32 f32 -> bf16
      int idx = (p * 256 + tid) * 8;
      int row = idx >> 5, col = idx & 31;
      const float* src = A + (size_t)(m0 + row) * Kdim + kk + col;
      float4 f0 = *(const float4*)src;
      float4 f1 = *(const float4*)(src + 4);
      u16x8 pk = { f2bf(f0.x), f2bf(f0.y), f2bf(f0.z), f2bf(f0.w),
                   f2bf(f1.x), f2bf(f1.y), f2bf(f1.z), f2bf(f1.w) };
      *(u16x8*)(As + row * 32 + col) = pk;
    }
    __syncthreads();
    GEMM_MFMA_BODY
  }
}

// A and Bt both packed bf16 in global.
__device__ __forceinline__ void gemm_tile_bf16A(const u16* __restrict__ A,
                                                const u16* __restrict__ Bt, int Kdim,
                                                int m0, int n0, u16* As, u16* Bs,
                                                f32x4 (&acc)[4][4]) {
  const int tid = threadIdx.x;
  const int lane = tid & 63, quad = lane >> 4, c = lane & 15;
  const int wr = (tid >> 6) >> 1, wc = (tid >> 6) & 1;
  for (int kk = 0; kk < Kdim; kk += 32) {
    __syncthreads();
#pragma unroll
    for (int r = 0; r < 2; ++r) {
      int bo = r * 4096 + tid * 16;
      int row = bo >> 6, colb = bo & 63;
      gld16(A  + (size_t)(m0 + row) * Kdim + kk + (colb >> 1), (u16*)((char*)As + bo));
      gld16(Bt + (size_t)(n0 + row) * Kdim + kk + (colb >> 1), (u16*)((char*)Bs + bo));
    }
    __syncthreads();
    GEMM_MFMA_BODY
  }
}

// z=0: Q -> Qp[b,s,h*64+d]; z=1: K -> Kp same; z=2: V -> Vt[bh][d][t] (transposed)
__launch_bounds__(256, 2)
__global__ void gemm_qkv(const float* __restrict__ q, const float* __restrict__ k,
                         const float* __restrict__ v, const u16* __restrict__ wt3,
                         u16* __restrict__ Qp, u16* __restrict__ Kp, u16* __restrict__ Vt) {
  __shared__ u16 As[128 * 32];
  __shared__ u16 Bs[128 * 32];
  const int z = blockIdx.z;
  const float* A = z == 0 ? q : (z == 1 ? k : v);
  const u16* Bt = wt3 + (size_t)z * EMB * EMB;
  const int m0 = blockIdx.y * 128, n0 = blockIdx.x * 128;
  f32x4 acc[4][4];
  const f32x4 fz = {0.f, 0.f, 0.f, 0.f};
#pragma unroll
  for (int i = 0; i < 4; ++i)
#pragma unroll
    for (int j = 0; j < 4; ++j) acc[i][j] = fz;
  gemm_tile_f32A(A, Bt, EMB, m0, n0, As, Bs, acc);
  const int tid = threadIdx.x, lane = tid & 63, quad = lane >> 4, c = lane & 15;
  const int wr = (tid >> 6) >> 1, wc = (tid >> 6) & 1;
  if (z < 2) {
    u16* C = z == 0 ? Qp : Kp;
#pragma unroll
    for (int i = 0; i < 4; ++i)
#pragma unroll
      for (int j = 0; j < 4; ++j)
#pragma unroll
        for (int r = 0; r < 4; ++r) {
          int row = m0 + wr * 64 + i * 16 + quad * 4 + r;
          int col = n0 + wc * 64 + j * 16 + c;
          C[(size_t)row * EMB + col] = f2bf(acc[i][j][r]);
        }
  } else {
#pragma unroll
    for (int i = 0; i < 4; ++i)
#pragma unroll
      for (int j = 0; j < 4; ++j) {
        int row = m0 + wr * 64 + i * 16 + quad * 4;   // + r -> consecutive s
        int col = n0 + wc * 64 + j * 16 + c;          // n = h*64+d
        int b = row >> 11, s = row & 2047;
        int h = col >> 6, d = col & 63;
        u16x4 pk;
#pragma unroll
        for (int r = 0; r < 4; ++r) pk[r] = f2bf(acc[i][j][r]);
        *(u16x4*)(Vt + ((size_t)(b * NH + h) * DK + d) * SS + s) = pk;
      }
  }
}

// final projection: A = AO (bf16), Bt = WT (bf16), C = float32 output
__launch_bounds__(256, 2)
__global__ void gemm_out(const u16* __restrict__ A, const u16* __restrict__ Bt,
                         float* __restrict__ C) {
  __shared__ u16 As[128 * 32];
  __shared__ u16 Bs[128 * 32];
  const int m0 = blockIdx.y * 128, n0 = blockIdx.x * 128;
  f32x4 acc[4][4];
  const f32x4 fz = {0.f, 0.f, 0.f, 0.f};
#pragma unroll
  for (int i = 0; i < 4; ++i)
#pragma unroll
    for (int j = 0; j < 4; ++j) acc[i][j] = fz;
  gemm_tile_bf16A(A, Bt, EMB, m0, n0, As, Bs, acc);
  const int tid = threadIdx.x, lane = tid & 63, quad = lane >> 4, c = lane & 15;
  const int wr = (tid >> 6) >> 1, wc = (tid >> 6) & 1;
#pragma unroll
  for (int i = 0; i < 4; ++i)
#pragma unroll
    for (int j = 0; j < 4; ++j)
#pragma unroll
      for (int r = 0; r < 4; ++r) {
        int row = m0 + wr * 64 + i * 16 + quad * 4 + r;
        int col = n0 + wc * 64 + j * 16 + c;
        C[(size_t)row * EMB + col] = acc[i][j][r];   // raw fp32, no quantization
      }
}

// ---------------- flash attention ----------------
// grid (16, 24): x = 128-row Q tile, y = b*12+h. 256 threads = 4 waves, 32 rows/wave.
__launch_bounds__(256, 2)
__global__ void attn(const u16* __restrict__ Qp, const u16* __restrict__ Kp,
                     const u16* __restrict__ Vt, const uint32_t* __restrict__ mbits,
                     u16* __restrict__ AO) {
  __shared__ u16 Qs[128 * 72];     // Q tile, stride 72
  __shared__ u16 KPs[128 * 136];   // K view stride 72; P view stride 136 (aliased)
  __shared__ u16 Vs[64 * 136];     // V^T tile [d][t], stride 136
  const int tid = threadIdx.x, wvi = tid >> 6, lane = tid & 63;
  const int quad = lane >> 4, c = lane & 15;
  const int bh = blockIdx.y, b = bh / NH, h = bh - b * NH;
  const int m0 = blockIdx.x * 128;
  const size_t qkbase = (size_t)b * SS * EMB + (size_t)h * DK;
  const size_t vtbase = (size_t)bh * DK * SS;

#pragma unroll
  for (int it = 0; it < 4; ++it) {           // Q tile: 128x64
    int idx = (it * 256 + tid) * 8;
    int row = idx >> 6, d0 = idx & 63;
    bf16x8 t = *(const bf16x8*)(Qp + qkbase + (size_t)(m0 + row) * EMB + d0);
    *(bf16x8*)(Qs + row * 72 + d0) = t;
  }

  float mr[2][4], lr[2][4];
  f32x4 o[2][4];
  const f32x4 fz = {0.f, 0.f, 0.f, 0.f};
#pragma unroll
  for (int i = 0; i < 2; ++i) {
#pragma unroll
    for (int r = 0; r < 4; ++r) { mr[i][r] = -1e5f; lr[i][r] = 0.f; }
#pragma unroll
    for (int n = 0; n < 4; ++n) o[i][n] = fz;
  }
  const uint32_t* mrow = mbits + (size_t)b * SS * (SS / 32);

  for (int t0 = 0; t0 < SS; t0 += 128) {
    __syncthreads();                          // prev iter done with KPs/Vs (covers Qs 1st iter)
#pragma unroll
    for (int it = 0; it < 4; ++it) {
      int idx = (it * 256 + tid) * 8;
      int krow = idx >> 6, kd = idx & 63;     // K tile 128x64
      bf16x8 kv = *(const bf16x8*)(Kp + qkbase + (size_t)(t0 + krow) * EMB + kd);
      *(bf16x8*)(KPs + krow * 72 + kd) = kv;
      int vd = idx >> 7, vtc = idx & 127;     // V^T tile 64x128
      bf16x8 vv = *(const bf16x8*)(Vt + vtbase + (size_t)vd * SS + t0 + vtc);
      *(bf16x8*)(Vs + vd * 136 + vtc) = vv;
    }
    __syncthreads();
    // S = Q K^T  (2 m-tiles x 8 n-tiles x K=64)
    f32x4 s[2][8];
#pragma unroll
    for (int i = 0; i < 2; ++i)
#pragma unroll
      for (int j = 0; j < 8; ++j) s[i][j] = fz;
#pragma unroll
    for (int ks = 0; ks < 2; ++ks) {
      bf16x8 aq[2];
#pragma unroll
      for (int i = 0; i < 2; ++i)
        aq[i] = *(const bf16x8*)(Qs + (wvi * 32 + i * 16 + c) * 72 + ks * 32 + quad * 8);
#pragma unroll
      for (int j = 0; j < 8; ++j) {
        bf16x8 bk = *(const bf16x8*)(KPs + (j * 16 + c) * 72 + ks * 32 + quad * 8);
#pragma unroll
        for (int i = 0; i < 2; ++i)
          s[i][j] = __builtin_amdgcn_mfma_f32_16x16x32_bf16(aq[i], bk, s[i][j], 0, 0, 0);
      }
    }
    // mask + online softmax; C-layout: row = quad*4+r, col = c (+16*j)
#pragma unroll
    for (int i = 0; i < 2; ++i)
#pragma unroll
      for (int r = 0; r < 4; ++r) {
        int srow = m0 + wvi * 32 + i * 16 + quad * 4 + r;
        const uint4 w4 = *(const uint4*)(mrow + (size_t)srow * (SS / 32) + (t0 >> 5));
        uint32_t wsel[4] = {w4.x, w4.y, w4.z, w4.w};
        float pv[8];
        uint32_t bits[8];
        float rmax = -3.0e38f;
#pragma unroll
        for (int j = 0; j < 8; ++j) {
          float sv = s[i][j][r] * 0.125f;
          uint32_t bit = (wsel[j >> 1] >> ((j & 1) * 16 + c)) & 1u;
          bits[j] = bit;
          pv[j] = sv;
          rmax = fmaxf(rmax, bit ? sv : -3.0e38f);
        }
#pragma unroll
        for (int off = 1; off < 16; off <<= 1) rmax = fmaxf(rmax, __shfl_xor(rmax, off));
        float mold = mr[i][r];
        float mnew = fmaxf(mold, rmax);       // >= -1e5 always (finite)
        float alpha = exp2f((mold - mnew) * LOG2E);
        float rsum = 0.f;
#pragma unroll
        for (int j = 0; j < 8; ++j) {
          float p = bits[j] ? exp2f((pv[j] - mnew) * LOG2E) : 0.f;
          pv[j] = p;
          rsum += p;
        }
#pragma unroll
        for (int off = 1; off < 16; off <<= 1) rsum += __shfl_xor(rsum, off);
        mr[i][r] = mnew;
        lr[i][r] = lr[i][r] * alpha + rsum;
#pragma unroll
        for (int n = 0; n < 4; ++n) o[i][n][r] = o[i][n][r] * alpha;
#pragma unroll
        for (int j = 0; j < 8; ++j) s[i][j][r] = pv[j];
      }
    __syncthreads();                          // all waves done reading K before P overwrite
#pragma unroll
    for (int i = 0; i < 2; ++i)
#pragma unroll
      for (int r = 0; r < 4; ++r)
#pragma unroll
        for (int j = 0; j < 8; ++j)
          KPs[(wvi * 32 + i * 16 + quad * 4 + r) * 136 + j * 16 + c] = f2bf(s[i][j][r]);
    // O += P V  (each wave reads only rows it wrote -> same-wave LDS ordering)
#pragma unroll
    for (int ks = 0; ks < 4; ++ks) {
      bf16x8 ap[2];
#pragma unroll
      for (int i = 0; i < 2; ++i)
        ap[i] = *(const bf16x8*)(KPs + (wvi * 32 + i * 16 + c) * 136 + ks * 32 + quad * 8);
#pragma unroll
      for (int n = 0; n < 4; ++n) {
        bf16x8 bv = *(const bf16x8*)(Vs + (n * 16 + c) * 136 + ks * 32 + quad * 8);
#pragma unroll
        for (int i = 0; i < 2; ++i)
          o[i][n] = __builtin_amdgcn_mfma_f32_16x16x32_bf16(ap[i], bv, o[i][n], 0, 0, 0);
      }
    }
  }
#pragma unroll
  for (int i = 0; i < 2; ++i)
#pragma unroll
    for (int r = 0; r < 4; ++r) {
      int srow = m0 + wvi * 32 + i * 16 + quad * 4 + r;
      float inv = 1.f / fmaxf(lr[i][r], 1e-20f);
#pragma unroll
      for (int n = 0; n < 4; ++n) {
        int d = n * 16 + c;
        AO[qkbase + (size_t)srow * EMB + d] = f2bf(o[i][n][r] * inv);
      }
    }
}

extern "C" void kernel_launch(void* const* d_in, const int* in_sizes, int n_in,
                              void* d_out, int out_size, void* d_ws, size_t ws_size,
                              hipStream_t stream) {
  const float* q  = (const float*)d_in[0];
  const float* k  = (const float*)d_in[1];
  const float* v  = (const float*)d_in[2];
  const int* mask = (const int*)d_in[3];
  const float* Wq = (const float*)d_in[4];
  const float* Wk = (const float*)d_in[5];
  const float* Wv = (const float*)d_in[6];
  const float* W  = (const float*)d_in[7];
  float* out = (float*)d_out;

  // d_out is 3145728 f32 = 12 MiB. Use it as scratch for Kp (6 MiB) + Vt (6 MiB),
  // both dead before gemm_out overwrites d_out with the final fp32 result.
  u16* Kp = (u16*)d_out;                    // [b,s,h*64+d] bf16
  u16* Vt = (u16*)d_out + 3145728;          // [bh][d][t]   bf16

  // ws usage: 11.5 MiB total.
  u16* ws    = (u16*)d_ws;
  u16* Qp    = ws;                          // 3145728 u16; AO aliases (per-block r-then-w)
  u16* WqkvT = ws + 3145728;                // 1769472 u16
  u16* WT    = ws + 3145728 + 1769472;      // 589824 u16
  uint32_t* mb = (uint32_t*)(ws + 5505024); // 262144 u32 = 1 MiB
  u16* AO = Qp;

  pack_wqkv<<<dim3(2304, 3), 256, 0, stream>>>(Wq, Wk, Wv, WqkvT);
  pack_wt<<<dim3(2304), 256, 0, stream>>>(W, WT);
  pack_mask<<<dim3(32768), 256, 0, stream>>>(mask, mb);
  gemm_qkv<<<dim3(6, 32, 3), 256, 0, stream>>>(q, k, v, WqkvT, Qp, Kp, Vt);
  attn<<<dim3(16, 24), 256, 0, stream>>>(Qp, Kp, Vt, mb, AO);
  gemm_out<<<dim3(6, 32), 256, 0, stream>>>(AO, WT, out);
}

// Round 4
// 279.291 us; speedup vs baseline: 1.2426x; 1.2426x over previous
//
#include <hip/hip_runtime.h>
#include <stdint.h>

typedef uint16_t u16;
typedef __attribute__((ext_vector_type(8))) short bf16x8;    // 8 bf16 (4 VGPRs)
typedef __attribute__((ext_vector_type(8))) uint16_t u16x8;
typedef __attribute__((ext_vector_type(4))) uint16_t u16x4;
typedef __attribute__((ext_vector_type(4))) float f32x4;     // MFMA C/D

#define EMB 768
#define NH 12
#define DK 64
#define BB 2
#define SS 2048
#define SCL 0.1803368801111244f   // 0.125 * log2(e)  (log2-domain scores)

// round-to-nearest-even f32 -> bf16
__device__ __forceinline__ u16 f2bf(float x) {
  union { float f; uint32_t u; } v; v.f = x;
  uint32_t r = v.u + 0x7fffu + ((v.u >> 16) & 1u);
  return (u16)(r >> 16);
}

__device__ __forceinline__ void gld16(const u16* g, u16* l) {
  __builtin_amdgcn_global_load_lds((const __attribute__((address_space(1))) void*)g,
                                   (__attribute__((address_space(3))) void*)l, 16, 0, 0);
}

// ---------------- pack kernels ----------------
__global__ void pack_wqkv(const float* __restrict__ wq, const float* __restrict__ wk,
                          const float* __restrict__ wv, u16* __restrict__ out) {
  const float* w = blockIdx.y == 0 ? wq : (blockIdx.y == 1 ? wk : wv);
  u16* o = out + (size_t)blockIdx.y * EMB * EMB;
  int t = blockIdx.x * 256 + threadIdx.x;
  int n = t / EMB, e = t - n * EMB;
  int h = n >> 6, d = n & 63;
  o[t] = f2bf(w[(h * EMB + e) * DK + d]);
}

__global__ void pack_wt(const float* __restrict__ w, u16* __restrict__ o) {
  int t = blockIdx.x * 256 + threadIdx.x;
  int n = t / EMB, e = t - n * EMB;
  o[t] = f2bf(w[e * EMB + n]);
}

__global__ void pack_mask(const int* __restrict__ mask, uint32_t* __restrict__ bits) {
  size_t t = (size_t)blockIdx.x * 256 + threadIdx.x;
  int m = mask[t];
  unsigned long long ball = __ballot(m != 0);
  if ((threadIdx.x & 31) == 0)
    bits[t >> 5] = (uint32_t)((threadIdx.x & 32) ? (ball >> 32) : ball);
}

// ---------------- pipelined GEMM cores (C = A * Bt^T), 128x128 tile ----------------
#define GEMM_MFMA_BODY(Ab, Bb)                                                  \
    bf16x8 af[4], bfr[4];                                                       \
    _Pragma("unroll")                                                           \
    for (int i = 0; i < 4; ++i)                                                 \
      af[i] = *(const bf16x8*)((Ab) + (wr * 64 + i * 16 + c) * 32 + quad * 8);  \
    _Pragma("unroll")                                                           \
    for (int j = 0; j < 4; ++j)                                                 \
      bfr[j] = *(const bf16x8*)((Bb) + (wc * 64 + j * 16 + c) * 32 + quad * 8); \
    _Pragma("unroll")                                                           \
    for (int i = 0; i < 4; ++i)                                                 \
      _Pragma("unroll")                                                         \
      for (int j = 0; j < 4; ++j)                                               \
        acc[i][j] = __builtin_amdgcn_mfma_f32_16x16x32_bf16(af[i], bfr[j], acc[i][j], 0, 0, 0);

// A f32 in global (cvt to bf16 while staging via regs); Bt packed bf16 via gld16.
// Double-buffered LDS (As/Bs = [2][128*32]), one barrier per K-step.
__device__ __forceinline__ void gemm_f32A_pipe(const float* __restrict__ A,
                                               const u16* __restrict__ Bt, int Kdim,
                                               int m0, int n0, u16* As, u16* Bs,
                                               f32x4 (&acc)[4][4]) {
  const int tid = threadIdx.x;
  const int lane = tid & 63, quad = lane >> 4, c = lane & 15;
  const int wr = (tid >> 6) >> 1, wc = (tid >> 6) & 1;
  float4 a0[2], a1[2];
#define LOAD_A(kk)                                                     \
  _Pragma("unroll")                                                    \
  for (int p = 0; p < 2; ++p) {                                        \
    int idx = (p * 256 + tid) * 8;                                     \
    const float* src = A + (size_t)(m0 + (idx >> 5)) * Kdim + (kk) + (idx & 31); \
    a0[p] = *(const float4*)src; a1[p] = *(const float4*)(src + 4);    \
  }
#define ISSUE_B(kk, buf)                                               \
  _Pragma("unroll")                                                    \
  for (int r = 0; r < 2; ++r) {                                        \
    int bo = r * 4096 + tid * 16;                                      \
    gld16(Bt + (size_t)(n0 + (bo >> 6)) * Kdim + (kk) + ((bo & 63) >> 1), \
          Bs + (buf) * 4096 + (bo >> 1));                              \
  }
  LOAD_A(0); ISSUE_B(0, 0);
  for (int kk = 0; kk < Kdim; kk += 32) {
    const int buf = (kk >> 5) & 1;
#pragma unroll
    for (int p = 0; p < 2; ++p) {                 // write A(kk) regs -> As[buf]
      int idx = (p * 256 + tid) * 8;
      u16x8 pk = { f2bf(a0[p].x), f2bf(a0[p].y), f2bf(a0[p].z), f2bf(a0[p].w),
                   f2bf(a1[p].x), f2bf(a1[p].y), f2bf(a1[p].z), f2bf(a1[p].w) };
      *(u16x8*)(As + buf * 4096 + (idx >> 5) * 32 + (idx & 31)) = pk;
    }
    __syncthreads();                              // drains B(kk) DMA + A writes
    if (kk + 32 < Kdim) { LOAD_A(kk + 32); ISSUE_B(kk + 32, buf ^ 1); }
    const u16* Ab = As + buf * 4096;
    const u16* Bb = Bs + buf * 4096;
    GEMM_MFMA_BODY(Ab, Bb)
  }
#undef LOAD_A
#undef ISSUE_B
}

// A and Bt both packed bf16, both via gld16, double-buffered, one barrier/step.
__device__ __forceinline__ void gemm_bf16A_pipe(const u16* __restrict__ A,
                                                const u16* __restrict__ Bt, int Kdim,
                                                int m0, int n0, u16* As, u16* Bs,
                                                f32x4 (&acc)[4][4]) {
  const int tid = threadIdx.x;
  const int lane = tid & 63, quad = lane >> 4, c = lane & 15;
  const int wr = (tid >> 6) >> 1, wc = (tid >> 6) & 1;
#define ISSUE_AB(kk, buf)                                              \
  _Pragma("unroll")                                                    \
  for (int r = 0; r < 2; ++r) {                                        \
    int bo = r * 4096 + tid * 16;                                      \
    gld16(A  + (size_t)(m0 + (bo >> 6)) * Kdim + (kk) + ((bo & 63) >> 1), \
          As + (buf) * 4096 + (bo >> 1));                              \
    gld16(Bt + (size_t)(n0 + (bo >> 6)) * Kdim + (kk) + ((bo & 63) >> 1), \
          Bs + (buf) * 4096 + (bo >> 1));                              \
  }
  ISSUE_AB(0, 0);
  for (int kk = 0; kk < Kdim; kk += 32) {
    const int buf = (kk >> 5) & 1;
    __syncthreads();                              // drains DMA(kk)
    if (kk + 32 < Kdim) { ISSUE_AB(kk + 32, buf ^ 1); }
    const u16* Ab = As + buf * 4096;
    const u16* Bb = Bs + buf * 4096;
    GEMM_MFMA_BODY(Ab, Bb)
  }
#undef ISSUE_AB
}

// z=0: Q -> Qp[b,s,h*64+d]; z=1: K -> Kp same; z=2: V -> Vt[bh][d][t]
__launch_bounds__(256, 2)
__global__ void gemm_qkv(const float* __restrict__ q, const float* __restrict__ k,
                         const float* __restrict__ v, const u16* __restrict__ wt3,
                         u16* __restrict__ Qp, u16* __restrict__ Kp, u16* __restrict__ Vt) {
  __shared__ u16 As[2 * 128 * 32];
  __shared__ u16 Bs[2 * 128 * 32];
  const int z = blockIdx.z;
  const float* A = z == 0 ? q : (z == 1 ? k : v);
  const u16* Bt = wt3 + (size_t)z * EMB * EMB;
  const int m0 = blockIdx.y * 128, n0 = blockIdx.x * 128;
  f32x4 acc[4][4];
  const f32x4 fz = {0.f, 0.f, 0.f, 0.f};
#pragma unroll
  for (int i = 0; i < 4; ++i)
#pragma unroll
    for (int j = 0; j < 4; ++j) acc[i][j] = fz;
  gemm_f32A_pipe(A, Bt, EMB, m0, n0, As, Bs, acc);
  const int tid = threadIdx.x, lane = tid & 63, quad = lane >> 4, c = lane & 15;
  const int wr = (tid >> 6) >> 1, wc = (tid >> 6) & 1;
  if (z < 2) {
    u16* C = z == 0 ? Qp : Kp;
#pragma unroll
    for (int i = 0; i < 4; ++i)
#pragma unroll
      for (int j = 0; j < 4; ++j)
#pragma unroll
        for (int r = 0; r < 4; ++r) {
          int row = m0 + wr * 64 + i * 16 + quad * 4 + r;
          int col = n0 + wc * 64 + j * 16 + c;
          C[(size_t)row * EMB + col] = f2bf(acc[i][j][r]);
        }
  } else {
#pragma unroll
    for (int i = 0; i < 4; ++i)
#pragma unroll
      for (int j = 0; j < 4; ++j) {
        int row = m0 + wr * 64 + i * 16 + quad * 4;   // + r -> consecutive s
        int col = n0 + wc * 64 + j * 16 + c;          // n = h*64+d
        int b = row >> 11, s = row & 2047;
        int h = col >> 6, d = col & 63;
        u16x4 pk;
#pragma unroll
        for (int r = 0; r < 4; ++r) pk[r] = f2bf(acc[i][j][r]);
        *(u16x4*)(Vt + ((size_t)(b * NH + h) * DK + d) * SS + s) = pk;
      }
  }
}

__launch_bounds__(256, 2)
__global__ void gemm_out(const u16* __restrict__ A, const u16* __restrict__ Bt,
                         float* __restrict__ C) {
  __shared__ u16 As[2 * 128 * 32];
  __shared__ u16 Bs[2 * 128 * 32];
  const int m0 = blockIdx.y * 128, n0 = blockIdx.x * 128;
  f32x4 acc[4][4];
  const f32x4 fz = {0.f, 0.f, 0.f, 0.f};
#pragma unroll
  for (int i = 0; i < 4; ++i)
#pragma unroll
    for (int j = 0; j < 4; ++j) acc[i][j] = fz;
  gemm_bf16A_pipe(A, Bt, EMB, m0, n0, As, Bs, acc);
  const int tid = threadIdx.x, lane = tid & 63, quad = lane >> 4, c = lane & 15;
  const int wr = (tid >> 6) >> 1, wc = (tid >> 6) & 1;
#pragma unroll
  for (int i = 0; i < 4; ++i)
#pragma unroll
    for (int j = 0; j < 4; ++j)
#pragma unroll
      for (int r = 0; r < 4; ++r) {
        int row = m0 + wr * 64 + i * 16 + quad * 4 + r;
        int col = n0 + wc * 64 + j * 16 + c;
        C[(size_t)row * EMB + col] = acc[i][j][r];   // raw fp32
      }
}

// ---------------- flash attention v2 ----------------
// grid (32, 24): x = 64-row Q tile, y = b*12+h. 4 waves, 16 rows/wave. Q in regs.
// Pipelined: K/V/mask tile t+1 loaded into regs while computing tile t.
__launch_bounds__(256, 3)
__global__ void attn(const u16* __restrict__ Qp, const u16* __restrict__ Kp,
                     const u16* __restrict__ Vt, const uint32_t* __restrict__ mbits,
                     u16* __restrict__ AO) {
  __shared__ __align__(16) u16 KPs[128 * 72];   // K stride 72; P view stride 136 (aliased)
  __shared__ __align__(16) u16 Vs[64 * 136];    // V^T tile [d][t]
  __shared__ __align__(16) uint32_t Ms[256];    // mask tile: 64 rows x 4 words
  const int tid = threadIdx.x, wvi = tid >> 6, lane = tid & 63;
  const int quad = lane >> 4, c = lane & 15;
  const int bh = blockIdx.y, b = bh / NH, h = bh - b * NH;
  const int m0 = blockIdx.x * 64;
  const size_t qkbase = (size_t)b * SS * EMB + (size_t)h * DK;
  const size_t vtbase = (size_t)bh * DK * SS;
  const uint32_t* mrow = mbits + (size_t)b * SS * 64;

  // Q fragments in registers: rows m0 + wvi*16 + c, k = ks*32 + quad*8 + [0..7]
  bf16x8 aq[2];
  {
    const u16* qr = Qp + qkbase + (size_t)(m0 + wvi * 16 + c) * EMB + quad * 8;
#pragma unroll
    for (int ks = 0; ks < 2; ++ks) aq[ks] = *(const bf16x8*)(qr + ks * 32);
  }

  bf16x8 kreg[4], vreg[4];
  uint32_t mreg;
#define LOAD_TILE(t0)                                                            \
  _Pragma("unroll")                                                              \
  for (int p = 0; p < 4; ++p) {                                                  \
    int idx = (p * 256 + tid) * 8;                                               \
    kreg[p] = *(const bf16x8*)(Kp + qkbase + (size_t)((t0) + (idx >> 6)) * EMB + (idx & 63)); \
    vreg[p] = *(const bf16x8*)(Vt + vtbase + (size_t)(idx >> 7) * SS + (t0) + (idx & 127));  \
  }                                                                              \
  mreg = mrow[(size_t)(m0 + (tid >> 2)) * 64 + ((t0) >> 5) + (tid & 3)];

  LOAD_TILE(0)

  float mr[4], lr[4];
  f32x4 o[4];
  const f32x4 fz = {0.f, 0.f, 0.f, 0.f};
#pragma unroll
  for (int r = 0; r < 4; ++r) { mr[r] = -3.0e38f; lr[r] = 0.f; }
#pragma unroll
  for (int n = 0; n < 4; ++n) o[n] = fz;

  for (int it = 0; it < 16; ++it) {
    const int t0 = it * 128;
    __syncthreads();                       // B0: prev-iter PV/Vs reads done
#pragma unroll
    for (int p = 0; p < 4; ++p) {          // stage tile t from regs
      int idx = (p * 256 + tid) * 8;
      *(bf16x8*)(KPs + (idx >> 6) * 72 + (idx & 63)) = kreg[p];
      *(bf16x8*)(Vs + (idx >> 7) * 136 + (idx & 127)) = vreg[p];
    }
    Ms[tid] = mreg;
    __syncthreads();                       // B1: staging visible
    if (it < 15) { LOAD_TILE(t0 + 128) }   // prefetch overlaps compute

    // S = Q K^T : 1 m-tile x 8 n-tiles x K=64
    f32x4 s[8];
#pragma unroll
    for (int j = 0; j < 8; ++j) s[j] = fz;
#pragma unroll
    for (int ks = 0; ks < 2; ++ks)
#pragma unroll
      for (int j = 0; j < 8; ++j) {
        bf16x8 bk = *(const bf16x8*)(KPs + (j * 16 + c) * 72 + ks * 32 + quad * 8);
        s[j] = __builtin_amdgcn_mfma_f32_16x16x32_bf16(aq[ks], bk, s[j], 0, 0, 0);
      }

    // online softmax in log2 domain; C-layout row = quad*4+r, col = j*16+c
    uint4 mw[4];
#pragma unroll
    for (int r = 0; r < 4; ++r)
      mw[r] = *(const uint4*)(Ms + (wvi * 16 + quad * 4 + r) * 4);
#pragma unroll
    for (int r = 0; r < 4; ++r) {
      uint32_t wsel[4] = {mw[r].x, mw[r].y, mw[r].z, mw[r].w};
      float tv[8];
      uint32_t bt[8];
      float rmax = -3.0e38f;
#pragma unroll
      for (int j = 0; j < 8; ++j) {
        tv[j] = s[j][r] * SCL;
        bt[j] = (wsel[j >> 1] >> ((j & 1) * 16 + c)) & 1u;
        rmax = fmaxf(rmax, bt[j] ? tv[j] : -3.0e38f);
      }
#pragma unroll
      for (int off = 1; off < 16; off <<= 1) rmax = fmaxf(rmax, __shfl_xor(rmax, off));
      float mold = mr[r];
      float mnew = fmaxf(mold, rmax);
      float alpha = exp2f(mold - mnew);
      float ls = 0.f;
#pragma unroll
      for (int j = 0; j < 8; ++j) {
        float p = bt[j] ? exp2f(tv[j] - mnew) : 0.f;
        s[j][r] = p;
        ls += p;
      }
      mr[r] = mnew;
      lr[r] = lr[r] * alpha + ls;          // per-lane partial; reduced at end
#pragma unroll
      for (int n = 0; n < 4; ++n) o[n][r] *= alpha;
    }
    __syncthreads();                       // B2: all QK reads of KPs done
    // write P (stride 136, aliases KPs), own rows only
#pragma unroll
    for (int r = 0; r < 4; ++r)
#pragma unroll
      for (int j = 0; j < 8; ++j)
        KPs[(wvi * 16 + quad * 4 + r) * 136 + j * 16 + c] = f2bf(s[j][r]);
    // O += P V (reads own-wave-written P rows: same-wave DS ordering)
#pragma unroll
    for (int ks = 0; ks < 4; ++ks) {
      bf16x8 ap = *(const bf16x8*)(KPs + (wvi * 16 + c) * 136 + ks * 32 + quad * 8);
#pragma unroll
      for (int n = 0; n < 4; ++n) {
        bf16x8 bv = *(const bf16x8*)(Vs + (n * 16 + c) * 136 + ks * 32 + quad * 8);
        o[n] = __builtin_amdgcn_mfma_f32_16x16x32_bf16(ap, bv, o[n], 0, 0, 0);
      }
    }
  }

#pragma unroll
  for (int r = 0; r < 4; ++r) {
    float ls = lr[r];
#pragma unroll
    for (int off = 1; off < 16; off <<= 1) ls += __shfl_xor(ls, off);
    float inv = 1.f / fmaxf(ls, 1e-20f);
    int srow = m0 + wvi * 16 + quad * 4 + r;
#pragma unroll
    for (int n = 0; n < 4; ++n)
      AO[qkbase + (size_t)srow * EMB + n * 16 + c] = f2bf(o[n][r] * inv);
  }
#undef LOAD_TILE
}

extern "C" void kernel_launch(void* const* d_in, const int* in_sizes, int n_in,
                              void* d_out, int out_size, void* d_ws, size_t ws_size,
                              hipStream_t stream) {
  const float* q  = (const float*)d_in[0];
  const float* k  = (const float*)d_in[1];
  const float* v  = (const float*)d_in[2];
  const int* mask = (const int*)d_in[3];
  const float* Wq = (const float*)d_in[4];
  const float* Wk = (const float*)d_in[5];
  const float* Wv = (const float*)d_in[6];
  const float* W  = (const float*)d_in[7];
  float* out = (float*)d_out;

  // d_out (12 MiB) as scratch for Kp + Vt, dead before gemm_out writes.
  u16* Kp = (u16*)d_out;                    // [b,s,h*64+d] bf16
  u16* Vt = (u16*)d_out + 3145728;          // [bh][d][t]   bf16

  // ws: 11.5 MiB
  u16* ws    = (u16*)d_ws;
  u16* Qp    = ws;                          // 3145728 u16; AO aliases
  u16* WqkvT = ws + 3145728;                // 1769472 u16
  u16* WT    = ws + 3145728 + 1769472;      // 589824 u16
  uint32_t* mb = (uint32_t*)(ws + 5505024); // 262144 u32
  u16* AO = Qp;

  pack_wqkv<<<dim3(2304, 3), 256, 0, stream>>>(Wq, Wk, Wv, WqkvT);
  pack_wt<<<dim3(2304), 256, 0, stream>>>(W, WT);
  pack_mask<<<dim3(32768), 256, 0, stream>>>(mask, mb);
  gemm_qkv<<<dim3(6, 32, 3), 256, 0, stream>>>(q, k, v, WqkvT, Qp, Kp, Vt);
  attn<<<dim3(32, 24), 256, 0, stream>>>(Qp, Kp, Vt, mb, AO);
  gemm_out<<<dim3(6, 32), 256, 0, stream>>>(AO, WT, out);
}